// Round 8
// baseline (1017.788 us; speedup 1.0000x reference)
//
#include <hip/hip_runtime.h>
#include <math.h>

// ---------------------------------------------------------------------------
// GATv2 2-layer GNN (N=50000, E=800000, IN=W=128, HEADS=4, HID=32, EDIM=16)
// R5: 906 us (agg 233x2, VALU 66%). R6: 821 us (agg 183.7x2, VALU 61.5%).
// R7: (1) aggregate: 4-stream online softmax (chain/4), (2) transform: LDS-free
//     scalar-A (kills DS-unit serialization), (3) classifier fused into
//     layer-1 aggregate (no hbuf write, one less kernel).
// NOTE: harness passes integer inputs as int32 ("integer -> const int*").
// ---------------------------------------------------------------------------

static inline size_t align256(size_t x) { return (x + 255) & ~size_t(255); }

__device__ __forceinline__ int clampi(int v, int lo, int hi) {
  return v < lo ? lo : (v > hi ? hi : v);
}

// ---- in-degree histogram (int atomics only) --------------------------------
__global__ void k_hist(const int* __restrict__ ei, int* __restrict__ cnt, int E, int n) {
  int i = blockIdx.x * blockDim.x + threadIdx.x;
  if (i >= E) return;
  int dst = clampi(ei[E + i], 0, n - 1);
  atomicAdd(&cnt[dst], 1);
}

// ---- exclusive scan of (cnt[i]+1) over n nodes, single block of 1024 -------
__global__ void k_scan(const int* __restrict__ cnt, int* __restrict__ row_ptr, int n) {
  const int T = 1024;
  __shared__ int wsum[16], wbase[16];
  int tid = threadIdx.x;
  int chunk = (n + T - 1) / T;
  int lo = tid * chunk; if (lo > n) lo = n;
  int hi = lo + chunk;  if (hi > n) hi = n;
  int s = 0;
  for (int i = lo; i < hi; ++i) s += cnt[i] + 1;
  int lane = tid & 63, w = tid >> 6;
  int incl = s;
  #pragma unroll
  for (int d = 1; d < 64; d <<= 1) {
    int v = __shfl_up(incl, d, 64);
    if (lane >= d) incl += v;
  }
  if (lane == 63) wsum[w] = incl;
  __syncthreads();
  if (tid == 0) {
    int a = 0;
    for (int i = 0; i < 16; ++i) { wbase[i] = a; a += wsum[i]; }
  }
  __syncthreads();
  int run = wbase[w] + (incl - s);   // exclusive prefix at this thread's chunk
  if (tid == 0) row_ptr[0] = 0;
  for (int i = lo; i < hi; ++i) { run += cnt[i] + 1; row_ptr[i + 1] = run; }
}

// ---- scatter edges (and self-loops) into CSR as int2{src,eid} --------------
__global__ void k_scatter(const int* __restrict__ ei, int* __restrict__ cursor,
                          int2* __restrict__ col, int E, int n) {
  int i = blockIdx.x * blockDim.x + threadIdx.x;
  if (i < E) {
    int src = clampi(ei[i], 0, n - 1);
    int dst = clampi(ei[E + i], 0, n - 1);
    int pos = atomicAdd(&cursor[dst], 1);
    col[pos] = make_int2(src, i);
  } else if (i < E + n) {
    int node = i - E;
    int pos = atomicAdd(&cursor[node], 1);
    col[pos] = make_int2(node, E + node);   // eid >= E marks the self-loop
  }
}

// ---- self-loop attr = mean of incoming ORIGINAL edge_attr, via CSR ---------
__global__ void k_loop_mean(const int* __restrict__ row_ptr, const int2* __restrict__ col,
                            const float* __restrict__ ea, float* __restrict__ lsum,
                            int n, int E) {
  int t = blockIdx.x * blockDim.x + threadIdx.x;
  if (t >= n * 16) return;
  int node = t >> 4, d = t & 15;
  int beg = row_ptr[node], end = row_ptr[node + 1];
  float s = 0.f;
  int c = 0;
  for (int i = beg; i < end; ++i) {
    int2 se = col[i];
    if (se.y < E) { s += ea[(size_t)se.y * 16 + d]; ++c; }
  }
  lsum[t] = s / (float)(c > 0 ? c : 1);
}

// ---- node transform, LDS-free: A rows via wave-uniform (scalar) loads ------
// ROWS=32 rows/block; thread c -> output col (c<128: Wl, else Wr).
// A[r][k] is uniform across the wave -> s_load through K$; B[k][c] coalesced.
#define TR_ROWS 32
__launch_bounds__(256)
__global__ void k_transform(const float* __restrict__ in, const float* __restrict__ Wl,
                            const float* __restrict__ bl, const float* __restrict__ Wr,
                            const float* __restrict__ br, float* __restrict__ xl,
                            float* __restrict__ xr, int n) {
  int tid = threadIdx.x;
  int row0 = blockIdx.x * TR_ROWS;
  int rows = n - row0; if (rows > TR_ROWS) rows = TR_ROWS;
  int cc = tid & 127;
  const float* B = (tid < 128) ? Wl : Wr;
  float bias = (tid < 128) ? bl[cc] : br[cc];
  float acc[TR_ROWS];
  #pragma unroll
  for (int r = 0; r < TR_ROWS; ++r) acc[r] = bias;
  const float* Ab = in + (size_t)row0 * 128;
  if (rows == TR_ROWS) {
    for (int k = 0; k < 128; k += 4) {
      float b0 = B[(k + 0) * 128 + cc], b1 = B[(k + 1) * 128 + cc];
      float b2 = B[(k + 2) * 128 + cc], b3 = B[(k + 3) * 128 + cc];
      #pragma unroll
      for (int r = 0; r < TR_ROWS; ++r) {
        float4 a = *(const float4*)(Ab + r * 128 + k);   // wave-uniform -> s_load
        acc[r] += a.x * b0 + a.y * b1 + a.z * b2 + a.w * b3;
      }
    }
  } else {
    for (int k = 0; k < 128; k += 4) {
      float b0 = B[(k + 0) * 128 + cc], b1 = B[(k + 1) * 128 + cc];
      float b2 = B[(k + 2) * 128 + cc], b3 = B[(k + 3) * 128 + cc];
      for (int r = 0; r < rows; ++r) {
        float4 a = *(const float4*)(Ab + r * 128 + k);
        acc[r] += a.x * b0 + a.y * b1 + a.z * b2 + a.w * b3;
      }
    }
  }
  float* op = (tid < 128) ? xl : xr;
  for (int r = 0; r < rows; ++r) op[(size_t)(row0 + r) * 128 + cc] = acc[r];
}

// ---- GATv2 aggregation: one wave per node, 4-stream online softmax ---------
// lane -> channels (2*lane, 2*lane+1), head = lane>>4.
// Wave-uniform CSR entries readfirstlane'd -> scalar loads for col/ea.
#define EDGE_STEP(SRC, EID, MX, DEN, A0, A1)                                     \
  do {                                                                           \
    const float* ep = ((EID) < E) ? (ea + (size_t)(EID) * 16)                    \
                                  : (loop_attr + (size_t)((EID) - E) * 16);      \
    float2 xlv = *(const float2*)(xl + (size_t)(SRC) * 128 + lane * 2);          \
    float4 v0 = ((const float4*)ep)[0];                                          \
    float4 v1 = ((const float4*)ep)[1];                                          \
    float4 v2 = ((const float4*)ep)[2];                                          \
    float4 v3 = ((const float4*)ep)[3];                                          \
    float eh0 = v0.x * we0[0] + v0.y * we0[1] + v0.z * we0[2] + v0.w * we0[3];   \
    float eh1 = v0.x * we1[0] + v0.y * we1[1] + v0.z * we1[2] + v0.w * we1[3];   \
    eh0 += v1.x * we0[4] + v1.y * we0[5] + v1.z * we0[6] + v1.w * we0[7];        \
    eh1 += v1.x * we1[4] + v1.y * we1[5] + v1.z * we1[6] + v1.w * we1[7];        \
    eh0 += v2.x * we0[8] + v2.y * we0[9] + v2.z * we0[10] + v2.w * we0[11];      \
    eh1 += v2.x * we1[8] + v2.y * we1[9] + v2.z * we1[10] + v2.w * we1[11];      \
    eh0 += v3.x * we0[12] + v3.y * we0[13] + v3.z * we0[14] + v3.w * we0[15];    \
    eh1 += v3.x * we1[12] + v3.y * we1[13] + v3.z * we1[14] + v3.w * we1[15];    \
    float m0 = xlv.x + xrv.x + eh0;                                              \
    float m1 = xlv.y + xrv.y + eh1;                                              \
    float l0 = fmaxf(m0, 0.2f * m0);  /* leaky_relu(0.2) */                      \
    float l1 = fmaxf(m1, 0.2f * m1);                                             \
    float p = l0 * att0 + l1 * att1;                                             \
    p += __shfl_xor(p, 1);                                                       \
    p += __shfl_xor(p, 2);                                                       \
    p += __shfl_xor(p, 4);                                                       \
    p += __shfl_xor(p, 8);                                                       \
    float nm = fmaxf(MX, p);                                                     \
    float sc = __expf(MX - nm);                                                  \
    float w  = __expf(p - nm);                                                   \
    DEN = DEN * sc + w;                                                          \
    A0  = A0 * sc + w * xlv.x;                                                   \
    A1  = A1 * sc + w * xlv.y;                                                   \
    MX  = nm;                                                                    \
  } while (0)

__launch_bounds__(256)
__global__ void k_aggregate(const float* __restrict__ xl, const float* __restrict__ xr,
                            const int* __restrict__ row_ptr, const int2* __restrict__ col,
                            const float* __restrict__ ea, const float* __restrict__ loop_attr,
                            const float* __restrict__ We, const float* __restrict__ att,
                            const float* __restrict__ bvec, float* __restrict__ outv,
                            const float* __restrict__ Wc, const float* __restrict__ bc,
                            int n, int E) {
  int wv = threadIdx.x >> 6, lane = threadIdx.x & 63;
  int node = blockIdx.x * 4 + wv;
  if (node >= n) return;
  int c0 = lane * 2, c1 = lane * 2 + 1;
  float we0[16], we1[16];
  #pragma unroll
  for (int d = 0; d < 16; ++d) {
    we0[d] = We[d * 128 + c0];
    we1[d] = We[d * 128 + c1];
  }
  float att0 = att[c0], att1 = att[c1];
  float2 xrv = *(const float2*)(xr + (size_t)node * 128 + lane * 2);
  int beg = __builtin_amdgcn_readfirstlane(row_ptr[node]);
  int end = __builtin_amdgcn_readfirstlane(row_ptr[node + 1]);
  float mA = -INFINITY, dA = 0.f, a0A = 0.f, a1A = 0.f;
  float mB = -INFINITY, dB = 0.f, a0B = 0.f, a1B = 0.f;
  float mC = -INFINITY, dC = 0.f, a0C = 0.f, a1C = 0.f;
  float mD = -INFINITY, dD = 0.f, a0D = 0.f, a1D = 0.f;
  int i = beg;
  for (; i + 3 < end; i += 4) {
    int2 s0 = col[i], s1 = col[i + 1], s2 = col[i + 2], s3 = col[i + 3];
    int srcA = __builtin_amdgcn_readfirstlane(s0.x);
    int eidA = __builtin_amdgcn_readfirstlane(s0.y);
    int srcB = __builtin_amdgcn_readfirstlane(s1.x);
    int eidB = __builtin_amdgcn_readfirstlane(s1.y);
    int srcC = __builtin_amdgcn_readfirstlane(s2.x);
    int eidC = __builtin_amdgcn_readfirstlane(s2.y);
    int srcD = __builtin_amdgcn_readfirstlane(s3.x);
    int eidD = __builtin_amdgcn_readfirstlane(s3.y);
    EDGE_STEP(srcA, eidA, mA, dA, a0A, a1A);
    EDGE_STEP(srcB, eidB, mB, dB, a0B, a1B);
    EDGE_STEP(srcC, eidC, mC, dC, a0C, a1C);
    EDGE_STEP(srcD, eidD, mD, dD, a0D, a1D);
  }
  for (; i < end; ++i) {
    int2 s0 = col[i];
    int srcA = __builtin_amdgcn_readfirstlane(s0.x);
    int eidA = __builtin_amdgcn_readfirstlane(s0.y);
    EDGE_STEP(srcA, eidA, mA, dA, a0A, a1A);
  }
  // merge 4 streams (deg>=1 -> at least one finite max; empty streams give exp(-inf)=0)
  float nm = fmaxf(fmaxf(mA, mB), fmaxf(mC, mD));
  float eA = __expf(mA - nm), eB = __expf(mB - nm);
  float eC = __expf(mC - nm), eD = __expf(mD - nm);
  float den  = dA * eA + dB * eB + dC * eC + dD * eD;
  float acc0 = a0A * eA + a0B * eB + a0C * eC + a0D * eD;
  float acc1 = a1A * eA + a1B * eB + a1C * eC + a1D * eD;
  float inv = 1.f / (den + 1e-16f);
  float2 bv = ((const float2*)bvec)[lane];
  float o0 = acc0 * inv + bv.x;
  float o1 = acc1 * inv + bv.y;
  // exact GELU (approximate=False)
  o0 = 0.5f * o0 * (1.f + erff(o0 * 0.70710678118654752f));
  o1 = 0.5f * o1 * (1.f + erff(o1 * 0.70710678118654752f));
  if (Wc) {
    // fused classifier: logits[node] = dot(h, Wc) + bc
    float part = o0 * Wc[c0] + o1 * Wc[c1];
    part += __shfl_xor(part, 1);
    part += __shfl_xor(part, 2);
    part += __shfl_xor(part, 4);
    part += __shfl_xor(part, 8);
    part += __shfl_xor(part, 16);
    part += __shfl_xor(part, 32);
    if (lane == 0) outv[node] = part + bc[0];
  } else {
    *(float2*)(outv + (size_t)node * 128 + lane * 2) = make_float2(o0, o1);
  }
}

// ---------------------------------------------------------------------------
extern "C" void kernel_launch(void* const* d_in, const int* in_sizes, int n_in,
                              void* d_out, int out_size, void* d_ws, size_t ws_size,
                              hipStream_t stream) {
  const float* x    = (const float*)d_in[0];
  const int*   ei   = (const int*)d_in[1];     // int32 (harness converts int64)
  const float* ea   = (const float*)d_in[2];
  const float* Wl0  = (const float*)d_in[3];
  const float* bl0  = (const float*)d_in[4];
  const float* Wr0  = (const float*)d_in[5];
  const float* br0  = (const float*)d_in[6];
  const float* We0  = (const float*)d_in[7];
  const float* att0 = (const float*)d_in[8];
  const float* b0   = (const float*)d_in[9];
  const float* Wl1  = (const float*)d_in[10];
  const float* bl1  = (const float*)d_in[11];
  const float* Wr1  = (const float*)d_in[12];
  const float* br1  = (const float*)d_in[13];
  const float* We1  = (const float*)d_in[14];
  const float* att1 = (const float*)d_in[15];
  const float* b1   = (const float*)d_in[16];
  const float* Wc   = (const float*)d_in[17];
  const float* bc   = (const float*)d_in[18];
  float* out = (float*)d_out;

  int n  = in_sizes[0] / 128;
  int E  = in_sizes[1] / 2;
  int Ep = E + n;

  char* ws = (char*)d_ws;
  size_t off = 0;
  auto alloc = [&](size_t bytes) { size_t o = off; off = align256(off + bytes); return o; };
  int*   cnt     = (int*)  (ws + alloc((size_t)n * 4));
  float* lsum    = (float*)(ws + alloc((size_t)n * 16 * 4));     // loop_attr
  int*   row_ptr = (int*)  (ws + alloc((size_t)(n + 1) * 4));
  int*   cursor  = (int*)  (ws + alloc((size_t)n * 4));
  int2*  col     = (int2*) (ws + alloc((size_t)Ep * 8));
  float* xl      = (float*)(ws + alloc((size_t)n * 128 * 4));
  float* xr      = (float*)(ws + alloc((size_t)n * 128 * 4));
  float* hbuf    = (float*)(ws + alloc((size_t)n * 128 * 4));
  (void)ws_size; (void)n_in; (void)out_size;

  // --- graph preprocessing (identical work every call) ---
  hipMemsetAsync(cnt, 0, (size_t)n * 4, stream);
  k_hist<<<(E + 255) / 256, 256, 0, stream>>>(ei, cnt, E, n);
  k_scan<<<1, 1024, 0, stream>>>(cnt, row_ptr, n);
  hipMemcpyAsync(cursor, row_ptr, (size_t)n * 4, hipMemcpyDeviceToDevice, stream);
  k_scatter<<<(Ep + 255) / 256, 256, 0, stream>>>(ei, cursor, col, E, n);
  k_loop_mean<<<(n * 16 + 255) / 256, 256, 0, stream>>>(row_ptr, col, ea, lsum, n, E);

  // --- layer 0 ---
  k_transform<<<(n + TR_ROWS - 1) / TR_ROWS, 256, 0, stream>>>(x, Wl0, bl0, Wr0, br0, xl, xr, n);
  k_aggregate<<<(n + 3) / 4, 256, 0, stream>>>(xl, xr, row_ptr, col, ea, lsum,
                                               We0, att0, b0, hbuf, nullptr, nullptr, n, E);
  // --- layer 1 (classifier fused: writes logits directly to out) ---
  k_transform<<<(n + TR_ROWS - 1) / TR_ROWS, 256, 0, stream>>>(hbuf, Wl1, bl1, Wr1, br1, xl, xr, n);
  k_aggregate<<<(n + 3) / 4, 256, 0, stream>>>(xl, xr, row_ptr, col, ea, lsum,
                                               We1, att1, b1, out, Wc, bc, n, E);
}

// Round 10
// 763.661 us; speedup vs baseline: 1.3328x; 1.3328x over previous
//
#include <hip/hip_runtime.h>
#include <math.h>

// ---------------------------------------------------------------------------
// GATv2 2-layer GNN (N=50000, E=800000, IN=W=128, HEADS=4, HID=32, EDIM=16)
// R5: 906us (agg 233x2). R6: 821us (agg 183.7x2, VALU 61.5%, occ 36%).
// R7: 1018us REGRESSION (4-stream agg 219x2: VGPR 68, occ 27.8%; LDS-free
//     transform +126us). Lesson: latency-hiding-bound; keep VGPR low.
// R9: agg = R6 2-stream + 1-pair prefetch pipeline (hide xl gather latency);
//     transform = R6 LDS version (measured-good); multi-block scan (no more
//     1-CU serial scan, no d2d memcpy); classifier stays fused.
// NOTE: harness passes integer inputs as int32 ("integer -> const int*").
// ---------------------------------------------------------------------------

static inline size_t align256(size_t x) { return (x + 255) & ~size_t(255); }

__device__ __forceinline__ int clampi(int v, int lo, int hi) {
  return v < lo ? lo : (v > hi ? hi : v);
}

// ---- in-degree histogram (int atomics only) --------------------------------
__global__ void k_hist(const int* __restrict__ ei, int* __restrict__ cnt, int E, int n) {
  int i = blockIdx.x * blockDim.x + threadIdx.x;
  if (i >= E) return;
  int dst = clampi(ei[E + i], 0, n - 1);
  atomicAdd(&cnt[dst], 1);
}

// ---- multi-block scan of (cnt[i]+1): 3 small kernels -----------------------
// scan1: per-block (1024 nodes) inclusive scan -> tmp, block total -> bsum
__global__ void k_scan1(const int* __restrict__ cnt, int* __restrict__ tmp,
                        int* __restrict__ bsum, int n) {
  __shared__ int wsum[4], wbase[4], total;
  int tid = threadIdx.x;
  int base = blockIdx.x * 1024 + tid * 4;
  int v0 = 0, v1 = 0, v2 = 0, v3 = 0;
  if (base + 3 < n) {
    int4 c = *(const int4*)(cnt + base);
    v0 = c.x + 1; v1 = c.y + 1; v2 = c.z + 1; v3 = c.w + 1;
  } else {
    if (base + 0 < n) v0 = cnt[base + 0] + 1;
    if (base + 1 < n) v1 = cnt[base + 1] + 1;
    if (base + 2 < n) v2 = cnt[base + 2] + 1;
  }
  int s = v0 + v1 + v2 + v3;
  int lane = tid & 63, w = tid >> 6;
  int incl = s;
  #pragma unroll
  for (int d = 1; d < 64; d <<= 1) {
    int v = __shfl_up(incl, d, 64);
    if (lane >= d) incl += v;
  }
  if (lane == 63) wsum[w] = incl;
  __syncthreads();
  if (tid == 0) {
    int a = 0;
    #pragma unroll
    for (int i = 0; i < 4; ++i) { wbase[i] = a; a += wsum[i]; }
    total = a;
  }
  __syncthreads();
  int excl = wbase[w] + (incl - s);
  int p0 = excl + v0, p1 = p0 + v1, p2 = p1 + v2, p3 = p2 + v3;
  if (base + 0 < n) tmp[base + 0] = p0;
  if (base + 1 < n) tmp[base + 1] = p1;
  if (base + 2 < n) tmp[base + 2] = p2;
  if (base + 3 < n) tmp[base + 3] = p3;
  if (tid == 0) bsum[blockIdx.x] = total;
}

// scan2: exclusive scan of block totals (nb <= 256), single tiny block
__global__ void k_scan2(int* __restrict__ bsum, int nb) {
  __shared__ int sh[256];
  int tid = threadIdx.x;
  sh[tid] = (tid < nb) ? bsum[tid] : 0;
  __syncthreads();
  if (tid == 0) {
    int a = 0;
    for (int i = 0; i < nb; ++i) { int t = sh[i]; sh[i] = a; a += t; }
  }
  __syncthreads();
  if (tid < nb) bsum[tid] = sh[tid];
}

// scan3: row_ptr[i+1] = tmp[i] + base[blk]; also fills cursor (= row starts)
__global__ void k_scan3(const int* __restrict__ tmp, const int* __restrict__ bsum,
                        int* __restrict__ row_ptr, int* __restrict__ cursor, int n) {
  int i = blockIdx.x * blockDim.x + threadIdx.x;
  if (i >= n) return;
  int v = tmp[i] + bsum[i >> 10];
  row_ptr[i + 1] = v;
  if (i + 1 < n) cursor[i + 1] = v;
  if (i == 0) { row_ptr[0] = 0; cursor[0] = 0; }
}

// ---- scatter edges (and self-loops) into CSR as int2{src,eid} --------------
__global__ void k_scatter(const int* __restrict__ ei, int* __restrict__ cursor,
                          int2* __restrict__ col, int E, int n) {
  int i = blockIdx.x * blockDim.x + threadIdx.x;
  if (i < E) {
    int src = clampi(ei[i], 0, n - 1);
    int dst = clampi(ei[E + i], 0, n - 1);
    int pos = atomicAdd(&cursor[dst], 1);
    col[pos] = make_int2(src, i);
  } else if (i < E + n) {
    int node = i - E;
    int pos = atomicAdd(&cursor[node], 1);
    col[pos] = make_int2(node, E + node);   // eid >= E marks the self-loop
  }
}

// ---- self-loop attr = mean of incoming ORIGINAL edge_attr, via CSR ---------
__global__ void k_loop_mean(const int* __restrict__ row_ptr, const int2* __restrict__ col,
                            const float* __restrict__ ea, float* __restrict__ lsum,
                            int n, int E) {
  int t = blockIdx.x * blockDim.x + threadIdx.x;
  if (t >= n * 16) return;
  int node = t >> 4, d = t & 15;
  int beg = row_ptr[node], end = row_ptr[node + 1];
  float s = 0.f;
  int c = 0;
  for (int i = beg; i < end; ++i) {
    int2 se = col[i];
    if (se.y < E) { s += ea[(size_t)se.y * 16 + d]; ++c; }
  }
  lsum[t] = s / (float)(c > 0 ? c : 1);
}

// ---- node transform (R6 LDS version, measured-good) ------------------------
__launch_bounds__(256)
__global__ void k_transform(const float* __restrict__ in, const float* __restrict__ Wl,
                            const float* __restrict__ bl, const float* __restrict__ Wr,
                            const float* __restrict__ br, float* __restrict__ xl,
                            float* __restrict__ xr, int n) {
  __shared__ float As[16][128];
  int tid = threadIdx.x;
  int row0 = blockIdx.x * 16;
  int rows = n - row0; if (rows > 16) rows = 16;
  const float4* in4 = (const float4*)(in + (size_t)row0 * 128);
  float4* As4 = (float4*)As;
  for (int i = tid; i < rows * 32; i += 256) As4[i] = in4[i];
  __syncthreads();
  int c = tid;
  const float* B = (c < 128) ? Wl : Wr;
  int cc = c & 127;
  float bias = (c < 128) ? bl[cc] : br[cc];
  float acc[16];
  #pragma unroll
  for (int i = 0; i < 16; ++i) acc[i] = bias;
  for (int k = 0; k < 128; k += 4) {
    float b0 = B[(k + 0) * 128 + cc], b1 = B[(k + 1) * 128 + cc];
    float b2 = B[(k + 2) * 128 + cc], b3 = B[(k + 3) * 128 + cc];
    #pragma unroll
    for (int r = 0; r < 16; ++r) {
      float4 a = *(const float4*)&As[r][k];   // LDS broadcast (uniform addr)
      acc[r] += a.x * b0 + a.y * b1 + a.z * b2 + a.w * b3;
    }
  }
  float* op = (c < 128) ? xl : xr;
  for (int r = 0; r < rows; ++r) op[(size_t)(row0 + r) * 128 + cc] = acc[r];
}

// ---- GATv2 aggregation: one wave per node, 2-stream + 1-pair prefetch ------
// lane -> channels (2*lane, 2*lane+1), head = lane>>4.
// EDGE_STEP_P consumes a PRELOADED xl value; ea via scalar (readfirstlane'd
// eid) loads. Next pair's col+xl issued before current pair's compute.
#define EDGE_STEP_P(EID, XLV, MX, DEN, A0, A1)                                   \
  do {                                                                           \
    const float* ep = ((EID) < E) ? (ea + (size_t)(EID) * 16)                    \
                                  : (loop_attr + (size_t)((EID) - E) * 16);      \
    float4 v0 = ((const float4*)ep)[0];                                          \
    float4 v1 = ((const float4*)ep)[1];                                          \
    float4 v2 = ((const float4*)ep)[2];                                          \
    float4 v3 = ((const float4*)ep)[3];                                          \
    float eh0 = v0.x * we0[0] + v0.y * we0[1] + v0.z * we0[2] + v0.w * we0[3];   \
    float eh1 = v0.x * we1[0] + v0.y * we1[1] + v0.z * we1[2] + v0.w * we1[3];   \
    eh0 += v1.x * we0[4] + v1.y * we0[5] + v1.z * we0[6] + v1.w * we0[7];        \
    eh1 += v1.x * we1[4] + v1.y * we1[5] + v1.z * we1[6] + v1.w * we1[7];        \
    eh0 += v2.x * we0[8] + v2.y * we0[9] + v2.z * we0[10] + v2.w * we0[11];      \
    eh1 += v2.x * we1[8] + v2.y * we1[9] + v2.z * we1[10] + v2.w * we1[11];      \
    eh0 += v3.x * we0[12] + v3.y * we0[13] + v3.z * we0[14] + v3.w * we0[15];    \
    eh1 += v3.x * we1[12] + v3.y * we1[13] + v3.z * we1[14] + v3.w * we1[15];    \
    float m0 = (XLV).x + xrv.x + eh0;                                            \
    float m1 = (XLV).y + xrv.y + eh1;                                            \
    float l0 = fmaxf(m0, 0.2f * m0);  /* leaky_relu(0.2) */                      \
    float l1 = fmaxf(m1, 0.2f * m1);                                             \
    float p = l0 * att0 + l1 * att1;                                             \
    p += __shfl_xor(p, 1);                                                       \
    p += __shfl_xor(p, 2);                                                       \
    p += __shfl_xor(p, 4);                                                       \
    p += __shfl_xor(p, 8);                                                       \
    float nm = fmaxf(MX, p);                                                     \
    float sc = __expf(MX - nm);                                                  \
    float w  = __expf(p - nm);                                                   \
    DEN = DEN * sc + w;                                                          \
    A0  = A0 * sc + w * (XLV).x;                                                 \
    A1  = A1 * sc + w * (XLV).y;                                                 \
    MX  = nm;                                                                    \
  } while (0)

__launch_bounds__(256)
__global__ void k_aggregate(const float* __restrict__ xl, const float* __restrict__ xr,
                            const int* __restrict__ row_ptr, const int2* __restrict__ col,
                            const float* __restrict__ ea, const float* __restrict__ loop_attr,
                            const float* __restrict__ We, const float* __restrict__ att,
                            const float* __restrict__ bvec, float* __restrict__ outv,
                            const float* __restrict__ Wc, const float* __restrict__ bc,
                            int n, int E) {
  int wv = threadIdx.x >> 6, lane = threadIdx.x & 63;
  int node = blockIdx.x * 4 + wv;
  if (node >= n) return;
  int c0 = lane * 2, c1 = c0 + 1;
  float we0[16], we1[16];
  #pragma unroll
  for (int d = 0; d < 16; ++d) {
    we0[d] = We[d * 128 + c0];
    we1[d] = We[d * 128 + c1];
  }
  float att0 = att[c0], att1 = att[c1];
  float2 xrv = *(const float2*)(xr + (size_t)node * 128 + c0);
  int beg = __builtin_amdgcn_readfirstlane(row_ptr[node]);
  int end = __builtin_amdgcn_readfirstlane(row_ptr[node + 1]);
  float mA = -INFINITY, dA = 0.f, a0A = 0.f, a1A = 0.f;
  float mB = -INFINITY, dB = 0.f, a0B = 0.f, a1B = 0.f;
  int i = beg;
  int eida = 0, eidb = 0;
  float2 xa = make_float2(0.f, 0.f), xb = make_float2(0.f, 0.f);
  if (i + 1 < end) {       // preload first pair
    int2 ca = col[i], cb = col[i + 1];
    int sa = __builtin_amdgcn_readfirstlane(ca.x);
    eida   = __builtin_amdgcn_readfirstlane(ca.y);
    int sb = __builtin_amdgcn_readfirstlane(cb.x);
    eidb   = __builtin_amdgcn_readfirstlane(cb.y);
    xa = *(const float2*)(xl + (size_t)sa * 128 + c0);
    xb = *(const float2*)(xl + (size_t)sb * 128 + c0);
  }
  for (; i + 3 < end; i += 2) {
    // issue next pair's loads before computing current pair
    int2 cna = col[i + 2], cnb = col[i + 3];
    int sna = __builtin_amdgcn_readfirstlane(cna.x);
    int ena = __builtin_amdgcn_readfirstlane(cna.y);
    int snb = __builtin_amdgcn_readfirstlane(cnb.x);
    int enb = __builtin_amdgcn_readfirstlane(cnb.y);
    float2 xna = *(const float2*)(xl + (size_t)sna * 128 + c0);
    float2 xnb = *(const float2*)(xl + (size_t)snb * 128 + c0);
    EDGE_STEP_P(eida, xa, mA, dA, a0A, a1A);
    EDGE_STEP_P(eidb, xb, mB, dB, a0B, a1B);
    eida = ena; eidb = enb; xa = xna; xb = xnb;
  }
  if (i + 1 < end) {       // last preloaded pair
    EDGE_STEP_P(eida, xa, mA, dA, a0A, a1A);
    EDGE_STEP_P(eidb, xb, mB, dB, a0B, a1B);
    i += 2;
  }
  if (i < end) {           // odd tail
    int2 c = col[i];
    int s  = __builtin_amdgcn_readfirstlane(c.x);
    int e2 = __builtin_amdgcn_readfirstlane(c.y);
    float2 xv = *(const float2*)(xl + (size_t)s * 128 + c0);
    EDGE_STEP_P(e2, xv, mA, dA, a0A, a1A);
  }
  // merge the two streams (deg>=1 -> mA finite; empty B gives exp(-inf)=0)
  float nm = fmaxf(mA, mB);
  float eA = __expf(mA - nm), eB = __expf(mB - nm);
  float den  = dA * eA + dB * eB;
  float acc0 = a0A * eA + a0B * eB;
  float acc1 = a1A * eA + a1B * eB;
  float inv = 1.f / (den + 1e-16f);
  float2 bv = ((const float2*)bvec)[lane];
  float o0 = acc0 * inv + bv.x;
  float o1 = acc1 * inv + bv.y;
  // exact GELU (approximate=False)
  o0 = 0.5f * o0 * (1.f + erff(o0 * 0.70710678118654752f));
  o1 = 0.5f * o1 * (1.f + erff(o1 * 0.70710678118654752f));
  if (Wc) {
    // fused classifier: logits[node] = dot(h, Wc) + bc
    float part = o0 * Wc[c0] + o1 * Wc[c1];
    part += __shfl_xor(part, 1);
    part += __shfl_xor(part, 2);
    part += __shfl_xor(part, 4);
    part += __shfl_xor(part, 8);
    part += __shfl_xor(part, 16);
    part += __shfl_xor(part, 32);
    if (lane == 0) outv[node] = part + bc[0];
  } else {
    *(float2*)(outv + (size_t)node * 128 + c0) = make_float2(o0, o1);
  }
}

// ---------------------------------------------------------------------------
extern "C" void kernel_launch(void* const* d_in, const int* in_sizes, int n_in,
                              void* d_out, int out_size, void* d_ws, size_t ws_size,
                              hipStream_t stream) {
  const float* x    = (const float*)d_in[0];
  const int*   ei   = (const int*)d_in[1];     // int32 (harness converts int64)
  const float* ea   = (const float*)d_in[2];
  const float* Wl0  = (const float*)d_in[3];
  const float* bl0  = (const float*)d_in[4];
  const float* Wr0  = (const float*)d_in[5];
  const float* br0  = (const float*)d_in[6];
  const float* We0  = (const float*)d_in[7];
  const float* att0 = (const float*)d_in[8];
  const float* b0   = (const float*)d_in[9];
  const float* Wl1  = (const float*)d_in[10];
  const float* bl1  = (const float*)d_in[11];
  const float* Wr1  = (const float*)d_in[12];
  const float* br1  = (const float*)d_in[13];
  const float* We1  = (const float*)d_in[14];
  const float* att1 = (const float*)d_in[15];
  const float* b1   = (const float*)d_in[16];
  const float* Wc   = (const float*)d_in[17];
  const float* bc   = (const float*)d_in[18];
  float* out = (float*)d_out;

  int n  = in_sizes[0] / 128;
  int E  = in_sizes[1] / 2;
  int Ep = E + n;
  int nb = (n + 1023) / 1024;

  char* ws = (char*)d_ws;
  size_t off = 0;
  auto alloc = [&](size_t bytes) { size_t o = off; off = align256(off + bytes); return o; };
  int*   cnt     = (int*)  (ws + alloc((size_t)n * 4));
  float* lsum    = (float*)(ws + alloc((size_t)n * 16 * 4));     // loop_attr
  int*   row_ptr = (int*)  (ws + alloc((size_t)(n + 1) * 4));
  int*   cursor  = (int*)  (ws + alloc((size_t)n * 4));
  int*   tmp     = (int*)  (ws + alloc((size_t)n * 4));
  int*   bsum    = (int*)  (ws + alloc(256 * 4));
  int2*  col     = (int2*) (ws + alloc((size_t)Ep * 8));
  float* xl      = (float*)(ws + alloc((size_t)n * 128 * 4));
  float* xr      = (float*)(ws + alloc((size_t)n * 128 * 4));
  float* hbuf    = (float*)(ws + alloc((size_t)n * 128 * 4));
  (void)ws_size; (void)n_in; (void)out_size;

  // --- graph preprocessing (identical work every call) ---
  hipMemsetAsync(cnt, 0, (size_t)n * 4, stream);
  k_hist<<<(E + 255) / 256, 256, 0, stream>>>(ei, cnt, E, n);
  k_scan1<<<nb, 256, 0, stream>>>(cnt, tmp, bsum, n);
  k_scan2<<<1, 256, 0, stream>>>(bsum, nb);
  k_scan3<<<(n + 255) / 256, 256, 0, stream>>>(tmp, bsum, row_ptr, cursor, n);
  k_scatter<<<(Ep + 255) / 256, 256, 0, stream>>>(ei, cursor, col, E, n);
  k_loop_mean<<<(n * 16 + 255) / 256, 256, 0, stream>>>(row_ptr, col, ea, lsum, n, E);

  // --- layer 0 ---
  k_transform<<<(n + 15) / 16, 256, 0, stream>>>(x, Wl0, bl0, Wr0, br0, xl, xr, n);
  k_aggregate<<<(n + 3) / 4, 256, 0, stream>>>(xl, xr, row_ptr, col, ea, lsum,
                                               We0, att0, b0, hbuf, nullptr, nullptr, n, E);
  // --- layer 1 (classifier fused: writes logits directly to out) ---
  k_transform<<<(n + 15) / 16, 256, 0, stream>>>(hbuf, Wl1, bl1, Wr1, br1, xl, xr, n);
  k_aggregate<<<(n + 3) / 4, 256, 0, stream>>>(xl, xr, row_ptr, col, ea, lsum,
                                               We1, att1, b1, out, Wc, bc, n, E);
}